// Round 10
// baseline (94.817 us; speedup 1.0000x reference)
//
#include <hip/hip_runtime.h>

#define EPS 1e-20f
typedef float f4 __attribute__((ext_vector_type(4)));

// ws layout (floats): [0,288)   sw  = softplus(spatial_weight) [c*9+k]
//                     [288,1312) cwT = softplus(channel_weight) transposed [c*32+o]
//                     [1312] 1/sum(sw), [1313] 1/sum(cw)
__global__ void prep_weights(const float* __restrict__ channel_weight, // [32*32] = [o][c]
                             const float* __restrict__ spatial_weight, // [32*9]
                             float* __restrict__ ws) {
    __shared__ float red[256];
    int tid = threadIdx.x;
    float local_sw = 0.f, local_cw = 0.f;
    for (int i = tid; i < 288; i += 256) {
        float x = spatial_weight[i];
        float v = fmaxf(x, 0.f) + log1pf(expf(-fabsf(x)));
        ws[i] = v;
        local_sw += v;
    }
    for (int i = tid; i < 1024; i += 256) {
        float x = channel_weight[i];   // i = o*32 + c
        float v = fmaxf(x, 0.f) + log1pf(expf(-fabsf(x)));
        int o = i >> 5, c = i & 31;
        ws[288 + c * 32 + o] = v;      // transposed store
        local_cw += v;
    }
    red[tid] = local_sw;
    __syncthreads();
    for (int s = 128; s > 0; s >>= 1) {
        if (tid < s) red[tid] += red[tid + s];
        __syncthreads();
    }
    if (tid == 0) ws[1312] = 1.0f / red[0];
    __syncthreads();
    red[tid] = local_cw;
    __syncthreads();
    for (int s = 128; s > 0; s >>= 1) {
        if (tid < s) red[tid] += red[tid + s];
        __syncthreads();
    }
    if (tid == 0) ws[1313] = 1.0f / red[0];
}

// R4 (fused3) structure: tile = (b, h, ct-half) = 1 row x 128 cols x 32 ch.
// Changes vs R4: LDS layout [c][pq*4+p] -> b128 LDS ops; t = nom*inv (no div).
// Stage 1: wave w, iter 0..3: c = w*8 + iter*2 + (lane>>5), quad pq = lane&31.
//   -> each load instruction = two dense 512B segments (one per channel).
// Stage 2: thread (og = tid>>5, pq = tid&31): 4 outputs x 4 px from LDS.
__global__ __launch_bounds__(256) void fused6(
    const float* __restrict__ d,
    const float* __restrict__ cd,
    const float* __restrict__ sp,     // [B,Cin,9,H,W]
    const float* __restrict__ wsbuf,
    const float* __restrict__ bias,   // [32]
    float* __restrict__ out)          // d_out [4,32,256,256] then cd_out
{
    __shared__ float lt[32 * 128];    // nom*inv_sum_sw,  [c][pq*4 + p]
    __shared__ float lc[32 * 128];    // cdsp = den*inv_sum_sw
    __shared__ float lcw[1024];       // [c][o]

    const int plane = 65536;

    // chunked XCD swizzle: XCD k (= orig%8) gets a contiguous bid range
    int bid = blockIdx.x;
    bid = (bid & 7) * 256 + (bid >> 3);

    const int ct = bid & 1;           // column half
    const int h  = (bid >> 1) & 255;
    const int b  = bid >> 9;

    const int tid = threadIdx.x;

    // cooperative: channel weights -> LDS (consumed after the barrier)
    #pragma unroll
    for (int i = 0; i < 4; ++i) lcw[i * 256 + tid] = wsbuf[288 + i * 256 + tid];

    // ---------------- stage 1 ----------------
    const int w    = tid >> 6;        // wave 0..3
    const int half = (tid >> 5) & 1;  // channel parity within wave
    const int pq   = tid & 31;        // quad within half-row
    const int col0 = ct * 128 + pq * 4;
    const float inv_sum_sw = wsbuf[1312];
    const bool rowv0 = (h >= 1), rowv2 = (h <= 254);

    #pragma unroll 1
    for (int iter = 0; iter < 4; ++iter) {
        const int c  = w * 8 + iter * 2 + half;
        const int bc = b * 32 + c;
        const float* __restrict__ dC  = d  + (size_t)bc * plane;
        const float* __restrict__ cdC = cd + (size_t)bc * plane;
        const float* __restrict__ spC = sp + (size_t)bc * 9 * plane + h * 256;

        f4 spv[9];
        #pragma unroll
        for (int k = 0; k < 9; ++k)
            spv[k] = __builtin_nontemporal_load((const f4*)(spC + (size_t)k * plane + col0));

        float dr[3][6], cr[3][6];     // cols col0-1 .. col0+4
        #pragma unroll
        for (int i = 0; i < 3; ++i) {
            const int hh = h + i - 1;
            const int hc = min(max(hh, 0), 255);
            const float* __restrict__ drow = dC  + hc * 256;
            const float* __restrict__ crow = cdC + hc * 256;
            f4 dv = *(const f4*)(drow + col0);
            f4 cv = *(const f4*)(crow + col0);
            dr[i][1] = dv[0]; dr[i][2] = dv[1]; dr[i][3] = dv[2]; dr[i][4] = dv[3];
            cr[i][1] = cv[0]; cr[i][2] = cv[1]; cr[i][3] = cv[2]; cr[i][4] = cv[3];
            dr[i][0] = drow[max(col0 - 1, 0)];
            cr[i][0] = crow[max(col0 - 1, 0)];
            dr[i][5] = drow[min(col0 + 4, 255)];
            cr[i][5] = crow[min(col0 + 4, 255)];
        }

        float swk[9];
        #pragma unroll
        for (int k = 0; k < 9; ++k) swk[k] = wsbuf[c * 9 + k];

        float nom[4] = {0.f, 0.f, 0.f, 0.f}, den[4] = {0.f, 0.f, 0.f, 0.f};
        #pragma unroll
        for (int i = 0; i < 3; ++i) {
            const bool rv = (i == 0) ? rowv0 : ((i == 2) ? rowv2 : true);
            #pragma unroll
            for (int j = 0; j < 3; ++j) {
                const int k = i * 3 + j;
                const float s = swk[k];
                #pragma unroll
                for (int p = 0; p < 4; ++p) {
                    const int ww = col0 + p + j - 1;
                    const bool valid = rv && ((unsigned)ww < 256u);
                    const float cdp = valid ? cr[i][p + j] * spv[k][p] : 0.f;
                    nom[p] = fmaf(cdp * dr[i][p + j], s, nom[p]);
                    den[p] = fmaf(cdp, s, den[p]);
                }
            }
        }

        // t = cdsp*dsp = (den*inv)*(nom/(den+EPS)) ~= nom*inv  (rel err EPS/(den+EPS))
        f4 tv, cv4;
        #pragma unroll
        for (int p = 0; p < 4; ++p) {
            tv[p]  = nom[p] * inv_sum_sw;
            cv4[p] = den[p] * inv_sum_sw;
        }
        *(f4*)&lt[c * 128 + pq * 4] = tv;      // single ds_write_b128
        *(f4*)&lc[c * 128 + pq * 4] = cv4;
    }

    __syncthreads();

    // ---------------- stage 2 ----------------
    const int og = tid >> 5;          // 0..7 -> o = og*4 .. og*4+3
    const int o0 = og * 4;

    float n2[4][4], d2[4][4];
    #pragma unroll
    for (int oi = 0; oi < 4; ++oi)
        #pragma unroll
        for (int j = 0; j < 4; ++j) { n2[oi][j] = 0.f; d2[oi][j] = 0.f; }

    for (int cc = 0; cc < 32; ++cc) {
        const f4 tq = *(const f4*)&lt[cc * 128 + pq * 4];   // ds_read_b128
        const f4 cq = *(const f4*)&lc[cc * 128 + pq * 4];   // lanes l/l+32 broadcast
        const f4 cw4 = *(const f4*)&lcw[cc * 32 + o0];
        #pragma unroll
        for (int oi = 0; oi < 4; ++oi)
            #pragma unroll
            for (int j = 0; j < 4; ++j) {
                n2[oi][j] = fmaf(tq[j], cw4[oi], n2[oi][j]);
                d2[oi][j] = fmaf(cq[j], cw4[oi], d2[oi][j]);
            }
    }

    const float inv_sum_cw = wsbuf[1313];
    const f4 b4 = *(const f4*)&bias[o0];
    const int colb = ct * 128 + pq * 4;

    #pragma unroll
    for (int oi = 0; oi < 4; ++oi) {
        f4 dv, cv;
        #pragma unroll
        for (int j = 0; j < 4; ++j) {
            dv[j] = n2[oi][j] / (d2[oi][j] + EPS) + b4[oi];
            cv[j] = d2[oi][j] * inv_sum_cw;   // STRIDE=1
        }
        const size_t po = (size_t)(b * 32 + o0 + oi) * plane + h * 256 + colb;
        *(f4*)(out + po)           = dv;
        *(f4*)(out + 8388608 + po) = cv;
    }
}

extern "C" void kernel_launch(void* const* d_in, const int* in_sizes, int n_in,
                              void* d_out, int out_size, void* d_ws, size_t ws_size,
                              hipStream_t stream) {
    const float* d    = (const float*)d_in[0];
    const float* cd   = (const float*)d_in[1];
    // d_in[2] = s, d_in[3] = cs : unused in forward
    const float* sp   = (const float*)d_in[4];
    const float* cwt  = (const float*)d_in[5];
    const float* swt  = (const float*)d_in[6];
    const float* bias = (const float*)d_in[7];
    float* out = (float*)d_out;
    float* ws  = (float*)d_ws;

    prep_weights<<<1, 256, 0, stream>>>(cwt, swt, ws);
    fused6<<<2048, 256, 0, stream>>>(d, cd, sp, ws, bias, out);
}

// Round 11
// 94.140 us; speedup vs baseline: 1.0072x; 1.0072x over previous
//
#include <hip/hip_runtime.h>

#define EPS 1e-20f
typedef float f4 __attribute__((ext_vector_type(4)));

// ws layout (floats): [0,288)   sw  = softplus(spatial_weight) [c*9+k]
//                     [288,1312) cwT = softplus(channel_weight) transposed [c*32+o]
//                     [1312] 1/sum(sw), [1313] 1/sum(cw)
__global__ void prep_weights(const float* __restrict__ channel_weight, // [32*32] = [o][c]
                             const float* __restrict__ spatial_weight, // [32*9]
                             float* __restrict__ ws) {
    __shared__ float red[256];
    int tid = threadIdx.x;
    float local_sw = 0.f, local_cw = 0.f;
    for (int i = tid; i < 288; i += 256) {
        float x = spatial_weight[i];
        float v = fmaxf(x, 0.f) + log1pf(expf(-fabsf(x)));
        ws[i] = v;
        local_sw += v;
    }
    for (int i = tid; i < 1024; i += 256) {
        float x = channel_weight[i];   // i = o*32 + c
        float v = fmaxf(x, 0.f) + log1pf(expf(-fabsf(x)));
        int o = i >> 5, c = i & 31;
        ws[288 + c * 32 + o] = v;      // transposed store
        local_cw += v;
    }
    red[tid] = local_sw;
    __syncthreads();
    for (int s = 128; s > 0; s >>= 1) {
        if (tid < s) red[tid] += red[tid + s];
        __syncthreads();
    }
    if (tid == 0) ws[1312] = 1.0f / red[0];
    __syncthreads();
    red[tid] = local_cw;
    __syncthreads();
    for (int s = 128; s > 0; s >>= 1) {
        if (tid < s) red[tid] += red[tid + s];
        __syncthreads();
    }
    if (tid == 0) ws[1313] = 1.0f / red[0];
}

// R4 (fused3) structure: tile = (b, h, ct-half) = 1 row x 128 cols x 32 ch.
// Changes vs R4: LDS layout [c][pq*4+p] -> b128 LDS ops; t = nom*inv (no div).
// Stage 1: wave w, iter 0..3: c = w*8 + iter*2 + (lane>>5), quad pq = lane&31.
//   -> each load instruction = two dense 512B segments (one per channel).
// Stage 2: thread (og = tid>>5, pq = tid&31): 4 outputs x 4 px from LDS.
__global__ __launch_bounds__(256) void fused6(
    const float* __restrict__ d,
    const float* __restrict__ cd,
    const float* __restrict__ sp,     // [B,Cin,9,H,W]
    const float* __restrict__ wsbuf,
    const float* __restrict__ bias,   // [32]
    float* __restrict__ out)          // d_out [4,32,256,256] then cd_out
{
    __shared__ float lt[32 * 128];    // nom*inv_sum_sw,  [c][pq*4 + p]
    __shared__ float lc[32 * 128];    // cdsp = den*inv_sum_sw
    __shared__ float lcw[1024];       // [c][o]

    const int plane = 65536;

    // chunked XCD swizzle: XCD k (= orig%8) gets a contiguous bid range
    int bid = blockIdx.x;
    bid = (bid & 7) * 256 + (bid >> 3);

    const int ct = bid & 1;           // column half
    const int h  = (bid >> 1) & 255;
    const int b  = bid >> 9;

    const int tid = threadIdx.x;

    // cooperative: channel weights -> LDS (consumed after the barrier)
    #pragma unroll
    for (int i = 0; i < 4; ++i) lcw[i * 256 + tid] = wsbuf[288 + i * 256 + tid];

    // ---------------- stage 1 ----------------
    const int w    = tid >> 6;        // wave 0..3
    const int half = (tid >> 5) & 1;  // channel parity within wave
    const int pq   = tid & 31;        // quad within half-row
    const int col0 = ct * 128 + pq * 4;
    const float inv_sum_sw = wsbuf[1312];
    const bool rowv0 = (h >= 1), rowv2 = (h <= 254);

    #pragma unroll 1
    for (int iter = 0; iter < 4; ++iter) {
        const int c  = w * 8 + iter * 2 + half;
        const int bc = b * 32 + c;
        const float* __restrict__ dC  = d  + (size_t)bc * plane;
        const float* __restrict__ cdC = cd + (size_t)bc * plane;
        const float* __restrict__ spC = sp + (size_t)bc * 9 * plane + h * 256;

        f4 spv[9];
        #pragma unroll
        for (int k = 0; k < 9; ++k)
            spv[k] = __builtin_nontemporal_load((const f4*)(spC + (size_t)k * plane + col0));

        float dr[3][6], cr[3][6];     // cols col0-1 .. col0+4
        #pragma unroll
        for (int i = 0; i < 3; ++i) {
            const int hh = h + i - 1;
            const int hc = min(max(hh, 0), 255);
            const float* __restrict__ drow = dC  + hc * 256;
            const float* __restrict__ crow = cdC + hc * 256;
            f4 dv = *(const f4*)(drow + col0);
            f4 cv = *(const f4*)(crow + col0);
            dr[i][1] = dv[0]; dr[i][2] = dv[1]; dr[i][3] = dv[2]; dr[i][4] = dv[3];
            cr[i][1] = cv[0]; cr[i][2] = cv[1]; cr[i][3] = cv[2]; cr[i][4] = cv[3];
            dr[i][0] = drow[max(col0 - 1, 0)];
            cr[i][0] = crow[max(col0 - 1, 0)];
            dr[i][5] = drow[min(col0 + 4, 255)];
            cr[i][5] = crow[min(col0 + 4, 255)];
        }

        float swk[9];
        #pragma unroll
        for (int k = 0; k < 9; ++k) swk[k] = wsbuf[c * 9 + k];

        float nom[4] = {0.f, 0.f, 0.f, 0.f}, den[4] = {0.f, 0.f, 0.f, 0.f};
        #pragma unroll
        for (int i = 0; i < 3; ++i) {
            const bool rv = (i == 0) ? rowv0 : ((i == 2) ? rowv2 : true);
            #pragma unroll
            for (int j = 0; j < 3; ++j) {
                const int k = i * 3 + j;
                const float s = swk[k];
                #pragma unroll
                for (int p = 0; p < 4; ++p) {
                    const int ww = col0 + p + j - 1;
                    const bool valid = rv && ((unsigned)ww < 256u);
                    const float cdp = valid ? cr[i][p + j] * spv[k][p] : 0.f;
                    nom[p] = fmaf(cdp * dr[i][p + j], s, nom[p]);
                    den[p] = fmaf(cdp, s, den[p]);
                }
            }
        }

        // t = cdsp*dsp = (den*inv)*(nom/(den+EPS)) ~= nom*inv  (rel err EPS/(den+EPS))
        f4 tv, cv4;
        #pragma unroll
        for (int p = 0; p < 4; ++p) {
            tv[p]  = nom[p] * inv_sum_sw;
            cv4[p] = den[p] * inv_sum_sw;
        }
        *(f4*)&lt[c * 128 + pq * 4] = tv;      // single ds_write_b128
        *(f4*)&lc[c * 128 + pq * 4] = cv4;
    }

    __syncthreads();

    // ---------------- stage 2 ----------------
    const int og = tid >> 5;          // 0..7 -> o = og*4 .. og*4+3
    const int o0 = og * 4;

    float n2[4][4], d2[4][4];
    #pragma unroll
    for (int oi = 0; oi < 4; ++oi)
        #pragma unroll
        for (int j = 0; j < 4; ++j) { n2[oi][j] = 0.f; d2[oi][j] = 0.f; }

    for (int cc = 0; cc < 32; ++cc) {
        const f4 tq = *(const f4*)&lt[cc * 128 + pq * 4];   // ds_read_b128
        const f4 cq = *(const f4*)&lc[cc * 128 + pq * 4];   // lanes l/l+32 broadcast
        const f4 cw4 = *(const f4*)&lcw[cc * 32 + o0];
        #pragma unroll
        for (int oi = 0; oi < 4; ++oi)
            #pragma unroll
            for (int j = 0; j < 4; ++j) {
                n2[oi][j] = fmaf(tq[j], cw4[oi], n2[oi][j]);
                d2[oi][j] = fmaf(cq[j], cw4[oi], d2[oi][j]);
            }
    }

    const float inv_sum_cw = wsbuf[1313];
    const f4 b4 = *(const f4*)&bias[o0];
    const int colb = ct * 128 + pq * 4;

    #pragma unroll
    for (int oi = 0; oi < 4; ++oi) {
        f4 dv, cv;
        #pragma unroll
        for (int j = 0; j < 4; ++j) {
            dv[j] = n2[oi][j] / (d2[oi][j] + EPS) + b4[oi];
            cv[j] = d2[oi][j] * inv_sum_cw;   // STRIDE=1
        }
        const size_t po = (size_t)(b * 32 + o0 + oi) * plane + h * 256 + colb;
        *(f4*)(out + po)           = dv;
        *(f4*)(out + 8388608 + po) = cv;
    }
}

extern "C" void kernel_launch(void* const* d_in, const int* in_sizes, int n_in,
                              void* d_out, int out_size, void* d_ws, size_t ws_size,
                              hipStream_t stream) {
    const float* d    = (const float*)d_in[0];
    const float* cd   = (const float*)d_in[1];
    // d_in[2] = s, d_in[3] = cs : unused in forward
    const float* sp   = (const float*)d_in[4];
    const float* cwt  = (const float*)d_in[5];
    const float* swt  = (const float*)d_in[6];
    const float* bias = (const float*)d_in[7];
    float* out = (float*)d_out;
    float* ws  = (float*)d_ws;

    prep_weights<<<1, 256, 0, stream>>>(cwt, swt, ws);
    fused6<<<2048, 256, 0, stream>>>(d, cd, sp, ws, bias, out);
}